// Round 2
// baseline (8763.849 us; speedup 1.0000x reference)
//
#include <hip/hip_runtime.h>
#include <stdint.h>

#define NLAYER 6
#define BATCH  128
#define HID    256
#define TSEQ   512
#define INFEAT 128
#define DEPTH  8          // h ring-buffer slots per layer (power of 2)
#define OUTN   10

typedef __attribute__((ext_vector_type(8))) short bf16x8;
typedef __attribute__((ext_vector_type(4))) float f32x4;

__device__ __forceinline__ short f2bf(float f) {
  union { float f; uint32_t u; } v; v.f = f;
  uint32_t r = v.u + 0x7fffu + ((v.u >> 16) & 1u);   // RNE
  return (short)(r >> 16);
}
__device__ __forceinline__ float bf2f(uint16_t b) {
  union { uint32_t u; float f; } v; v.u = ((uint32_t)b) << 16;
  return v.f;
}
// convert 8 consecutive fp32 (32B aligned) to a bf16x8 fragment
__device__ __forceinline__ bf16x8 cvt8(const float* p) {
  f32x4 a = *(const f32x4*)p;
  f32x4 b = *(const f32x4*)(p + 4);
  bf16x8 r;
  r[0] = f2bf(a[0]); r[1] = f2bf(a[1]); r[2] = f2bf(a[2]); r[3] = f2bf(a[3]);
  r[4] = f2bf(b[0]); r[5] = f2bf(b[1]); r[6] = f2bf(b[2]); r[7] = f2bf(b[3]);
  return r;
}
__device__ __forceinline__ float sigm(float x)  { return 1.0f / (1.0f + __expf(-x)); }
__device__ __forceinline__ float tanhff(float x){ return 1.0f - 2.0f / (__expf(2.0f * x) + 1.0f); }

// 192 blocks: 6 layers x 4 batch-slices(32) x 8 unit-groups(32 units).
// Wave (of 4): wm = M-tile (16 batch rows), wu = 16-unit half.
// Weights: register-resident bf16 fragments, 64 frags (256 VGPR) per thread.
__global__ void __launch_bounds__(256, 1)
lstm_pipeline(const float* __restrict__ xin, const float* __restrict__ h0,
              const float* __restrict__ c0,  const float* __restrict__ wih,
              const float* __restrict__ whh, const float* __restrict__ bih,
              const float* __restrict__ bhh, const float* __restrict__ fcw,
              const float* __restrict__ fcb, float* __restrict__ out,
              int* cnt, uint16_t* hbuf)
{
  // ---- id decode: siblings of one (layer,bslice) share bid%8 (= likely XCD) ----
  const int bid  = blockIdx.x;
  const int xcd  = bid & 7;
  const int slot = bid >> 3;                 // 0..23
  const int grp  = (slot >> 3) * 8 + xcd;    // 0..23  (layer,bslice) group
  const int cg   = slot & 7;                 // unit-group 0..7
  const int l  = grp >> 2;
  const int bs = grp & 3;

  const int tid  = threadIdx.x;
  const int wv   = tid >> 6, lane = tid & 63;
  const int wm   = wv & 1,  wu   = wv >> 1;
  const int l15  = lane & 15, l4 = lane >> 4;

  // ---- resident weight fragments: wf[mat][gate][kblock] ----
  bf16x8 wf[2][4][8];
  float  bias[4];
  {
    const float* Wl[2] = { wih + (size_t)l * 1024 * 256,
                           whh + (size_t)l * 1024 * 256 };
#pragma unroll
    for (int mat = 0; mat < 2; ++mat) {
#pragma unroll
      for (int gt = 0; gt < 4; ++gt) {
        const int Rg = gt * 256 + cg * 32 + wu * 16 + l15;  // gate-row (B j = lane&15)
        const float* rp = Wl[mat] + (size_t)Rg * 256 + l4 * 8;
#pragma unroll
        for (int kk = 0; kk < 8; ++kk)
          wf[mat][gt][kk] = cvt8(rp + kk * 32);
      }
    }
#pragma unroll
    for (int gt = 0; gt < 4; ++gt) {
      const int Rg = gt * 256 + cg * 32 + wu * 16 + l15;
      bias[gt] = bih[l * 1024 + Rg] + bhh[l * 1024 + Rg];
    }
  }

  const int ucol  = cg * 32 + wu * 16 + l15;   // this lane's hidden unit (C/D col)
  const int mrowA = bs * 32 + wm * 16 + l15;   // A-fragment batch row
  const int mrow0 = bs * 32 + wm * 16 + l4*4;  // C/D batch-row base (+j)

  float c[4];
#pragma unroll
  for (int j = 0; j < 4; ++j)
    c[j] = c0[((size_t)l * BATCH + (mrow0 + j)) * HID + ucol];

  int* cntP = cnt + (l * 4 + bs) * (TSEQ + 1);
  int* cntX = (l > 0) ? cnt + ((l - 1) * 4 + bs) * (TSEQ + 1) : nullptr;
  int* cntC = (l < 5) ? cnt + ((l + 1) * 4 + bs) * (TSEQ + 1) : nullptr;

  const uint16_t* hbL = hbuf + (size_t)l * DEPTH * BATCH * HID;
  const uint16_t* hbX = (l > 0) ? hbuf + (size_t)(l - 1) * DEPTH * BATCH * HID : nullptr;
  uint16_t*       hbO = hbuf + (size_t)l * DEPTH * BATCH * HID;

  int consDone = -1;   // highest t' with cnt[l+1][bs][t'] == 8 observed

  for (int t = 0; t < TSEQ; ++t) {
    f32x4 acc[4];
#pragma unroll
    for (int gt = 0; gt < 4; ++gt) { f32x4 a = {bias[gt], bias[gt], bias[gt], bias[gt]}; acc[gt] = a; }

    // ---------------- x part (input GEMM, folded per step) ----------------
    if (l == 0) {
      // raw input, fp32, only 128 features (cols 128..255 are the zero-pad)
      const float* xp = xin + ((size_t)mrowA * TSEQ + t) * INFEAT + l4 * 8;
#pragma unroll
      for (int kk = 0; kk < 4; ++kk) {
        bf16x8 af = cvt8(xp + kk * 32);
#pragma unroll
        for (int gt = 0; gt < 4; ++gt)
          acc[gt] = __builtin_amdgcn_mfma_f32_16x16x32_bf16(af, wf[0][gt][kk], acc[gt], 0, 0, 0);
      }
    } else {
      while (__hip_atomic_load(&cntX[t], __ATOMIC_ACQUIRE, __HIP_MEMORY_SCOPE_AGENT) < 8)
        __builtin_amdgcn_s_sleep(1);
      const uint16_t* hp = hbX + ((size_t)(t & (DEPTH - 1)) * BATCH + mrowA) * HID + l4 * 8;
#pragma unroll
      for (int kk = 0; kk < 8; ++kk) {
        bf16x8 af = *(const bf16x8*)(hp + kk * 32);
#pragma unroll
        for (int gt = 0; gt < 4; ++gt)
          acc[gt] = __builtin_amdgcn_mfma_f32_16x16x32_bf16(af, wf[0][gt][kk], acc[gt], 0, 0, 0);
      }
    }

    // ---------------- h part (recurrent GEMM) ----------------
    if (t == 0) {
      const float* hp = h0 + ((size_t)l * BATCH + mrowA) * HID + l4 * 8;
#pragma unroll
      for (int kk = 0; kk < 8; ++kk) {
        bf16x8 af = cvt8(hp + kk * 32);
#pragma unroll
        for (int gt = 0; gt < 4; ++gt)
          acc[gt] = __builtin_amdgcn_mfma_f32_16x16x32_bf16(af, wf[1][gt][kk], acc[gt], 0, 0, 0);
      }
    } else {
      while (__hip_atomic_load(&cntP[t - 1], __ATOMIC_ACQUIRE, __HIP_MEMORY_SCOPE_AGENT) < 8)
        __builtin_amdgcn_s_sleep(1);
      const uint16_t* hp = hbL + ((size_t)((t - 1) & (DEPTH - 1)) * BATCH + mrowA) * HID + l4 * 8;
#pragma unroll
      for (int kk = 0; kk < 8; ++kk) {
        bf16x8 af = *(const bf16x8*)(hp + kk * 32);
#pragma unroll
        for (int gt = 0; gt < 4; ++gt)
          acc[gt] = __builtin_amdgcn_mfma_f32_16x16x32_bf16(af, wf[1][gt][kk], acc[gt], 0, 0, 0);
      }
    }

    // ---------------- backpressure: don't overwrite slot still being read ----------------
    if (l < 5 && t >= DEPTH) {
      const int need = t - DEPTH;
      while (consDone < need) {
        int v = __hip_atomic_load(&cntC[consDone + 1], __ATOMIC_RELAXED, __HIP_MEMORY_SCOPE_AGENT);
        if (v == 8) ++consDone; else __builtin_amdgcn_s_sleep(2);
      }
    }

    // ---------------- gates, state update, h store ----------------
    uint16_t* op = hbO + (size_t)(t & (DEPTH - 1)) * BATCH * HID;
#pragma unroll
    for (int j = 0; j < 4; ++j) {
      float iv = sigm(acc[0][j]);
      float fv = sigm(acc[1][j]);
      float gv = tanhff(acc[2][j]);
      float ov = sigm(acc[3][j]);
      float cc = fv * c[j] + iv * gv;
      c[j] = cc;
      float hv = ov * tanhff(cc);
      op[(size_t)(mrow0 + j) * HID + ucol] = (uint16_t)f2bf(hv);
    }
    __syncthreads();   // drains vmcnt -> all 4 waves' stores complete
    if (tid == 0)
      __hip_atomic_fetch_add(&cntP[t], 1, __ATOMIC_RELEASE, __HIP_MEMORY_SCOPE_AGENT);
  }

  // ---------------- FC head: one WG per batch slice ----------------
  if (l == 5 && cg == 0) {
    while (__hip_atomic_load(&cntP[TSEQ - 1], __ATOMIC_ACQUIRE, __HIP_MEMORY_SCOPE_AGENT) < 8)
      __builtin_amdgcn_s_sleep(1);
    const uint16_t* hp = hbL + (size_t)((TSEQ - 1) & (DEPTH - 1)) * BATCH * HID;
    for (int p = tid; p < 32 * OUTN; p += 256) {
      const int mr = bs * 32 + p / OUTN, oc = p % OUTN;
      float a = fcb[oc];
      const uint16_t* hr = hp + (size_t)mr * HID;
      const float* wr = fcw + oc * HID;
#pragma unroll 8
      for (int uu = 0; uu < HID; ++uu)
        a += bf2f(hr[uu]) * wr[uu];
      out[mr * OUTN + oc] = a;
    }
  }
}

extern "C" void kernel_launch(void* const* d_in, const int* in_sizes, int n_in,
                              void* d_out, int out_size, void* d_ws, size_t ws_size,
                              hipStream_t stream) {
  const float* xin = (const float*)d_in[0];
  const float* h0  = (const float*)d_in[1];
  const float* c0  = (const float*)d_in[2];
  const float* wih = (const float*)d_in[3];
  const float* whh = (const float*)d_in[4];
  const float* bih = (const float*)d_in[5];
  const float* bhh = (const float*)d_in[6];
  const float* fcw = (const float*)d_in[7];
  const float* fcb = (const float*)d_in[8];
  float* out = (float*)d_out;

  int* cnt = (int*)d_ws;                       // 24 * 513 * 4B < 64KB
  const size_t cntBytes = 64 * 1024;
  uint16_t* hbuf = (uint16_t*)((char*)d_ws + cntBytes);  // 6*8*128*256*2B ~= 3.1MB

  hipMemsetAsync(d_ws, 0, cntBytes, stream);   // counters start at 0
  lstm_pipeline<<<dim3(192), dim3(256), 0, stream>>>(
      xin, h0, c0, wih, whh, bih, bhh, fcw, fcb, out, cnt, hbuf);
}

// Round 3
// 3991.500 us; speedup vs baseline: 2.1956x; 2.1956x over previous
//
#include <hip/hip_runtime.h>
#include <stdint.h>

#define NLAYER 6
#define BATCH  128
#define HID    256
#define TSEQ   512
#define INFEAT 128
#define DEPTH  8          // h ring-buffer slots per layer (power of 2)
#define OUTN   10

typedef __attribute__((ext_vector_type(8))) short bf16x8;
typedef __attribute__((ext_vector_type(4))) float f32x4;

__device__ __forceinline__ short f2bf(float f) {
  union { float f; uint32_t u; } v; v.f = f;
  uint32_t r = v.u + 0x7fffu + ((v.u >> 16) & 1u);   // RNE
  return (short)(r >> 16);
}
__device__ __forceinline__ float bf2f(uint32_t b) {
  union { uint32_t u; float f; } v; v.u = b << 16;
  return v.f;
}
// convert 8 consecutive fp32 (32B aligned) to a bf16x8 fragment
__device__ __forceinline__ bf16x8 cvt8(const float* p) {
  f32x4 a = *(const f32x4*)p;
  f32x4 b = *(const f32x4*)(p + 4);
  bf16x8 r;
  r[0] = f2bf(a[0]); r[1] = f2bf(a[1]); r[2] = f2bf(a[2]); r[3] = f2bf(a[3]);
  r[4] = f2bf(b[0]); r[5] = f2bf(b[1]); r[6] = f2bf(b[2]); r[7] = f2bf(b[3]);
  return r;
}
__device__ __forceinline__ float sigm(float x)  { return 1.0f / (1.0f + __expf(-x)); }
__device__ __forceinline__ float tanhff(float x){ return 1.0f - 2.0f / (__expf(2.0f * x) + 1.0f); }

// Device-coherent (L2-bypassing) h-ring access: no acquire/release cache ops
// are ever needed because these accesses interact at the coherent point.
__device__ __forceinline__ bf16x8 load_frag_dc(const uint16_t* p) {
  union { unsigned long long q[2]; bf16x8 v; } u;
  u.q[0] = __hip_atomic_load((const unsigned long long*)p,
                             __ATOMIC_RELAXED, __HIP_MEMORY_SCOPE_AGENT);
  u.q[1] = __hip_atomic_load((const unsigned long long*)(p + 4),
                             __ATOMIC_RELAXED, __HIP_MEMORY_SCOPE_AGENT);
  return u.v;
}
__device__ __forceinline__ void store_u16_dc(uint16_t* p, uint16_t v) {
  __hip_atomic_store(p, v, __ATOMIC_RELAXED, __HIP_MEMORY_SCOPE_AGENT);
}
__device__ __forceinline__ int load_flag(const int* p) {
  return __hip_atomic_load(p, __ATOMIC_RELAXED, __HIP_MEMORY_SCOPE_AGENT);
}

// 192 blocks: 6 layers x 4 batch-slices(32) x 8 unit-groups(32 units).
// Wave (of 4): wm = M-tile (16 batch rows), wu = 16-unit half.
// Weights: register-resident bf16 fragments per thread.
__global__ void __launch_bounds__(256, 1)
lstm_pipeline(const float* __restrict__ xin, const float* __restrict__ h0,
              const float* __restrict__ c0,  const float* __restrict__ wih,
              const float* __restrict__ whh, const float* __restrict__ bih,
              const float* __restrict__ bhh, const float* __restrict__ fcw,
              const float* __restrict__ fcb, float* __restrict__ out,
              int* cnt, uint16_t* hbuf)
{
  // ---- id decode: siblings of one (layer,bslice) share bid%8 (= likely XCD) ----
  const int bid  = blockIdx.x;
  const int xcd  = bid & 7;
  const int slot = bid >> 3;                 // 0..23
  const int grp  = (slot >> 3) * 8 + xcd;    // 0..23  (layer,bslice) group
  const int cg   = slot & 7;                 // unit-group 0..7
  const int l  = grp >> 2;
  const int bs = grp & 3;

  const int tid  = threadIdx.x;
  const int wv   = tid >> 6, lane = tid & 63;
  const int wm   = wv & 1,  wu   = wv >> 1;
  const int l15  = lane & 15, l4 = lane >> 4;

  // ---- resident weight fragments: wf[mat][gate][kblock] ----
  bf16x8 wf[2][4][8];
  float  bias[4];
  {
    const float* Wl[2] = { wih + (size_t)l * 1024 * 256,
                           whh + (size_t)l * 1024 * 256 };
#pragma unroll
    for (int mat = 0; mat < 2; ++mat) {
#pragma unroll
      for (int gt = 0; gt < 4; ++gt) {
        const int Rg = gt * 256 + cg * 32 + wu * 16 + l15;  // gate-row (B j = lane&15)
        const float* rp = Wl[mat] + (size_t)Rg * 256 + l4 * 8;
#pragma unroll
        for (int kk = 0; kk < 8; ++kk)
          wf[mat][gt][kk] = cvt8(rp + kk * 32);
      }
    }
#pragma unroll
    for (int gt = 0; gt < 4; ++gt) {
      const int Rg = gt * 256 + cg * 32 + wu * 16 + l15;
      bias[gt] = bih[l * 1024 + Rg] + bhh[l * 1024 + Rg];
    }
  }

  const int ucol  = cg * 32 + wu * 16 + l15;   // this lane's hidden unit (C/D col)
  const int mrowA = bs * 32 + wm * 16 + l15;   // A-fragment batch row
  const int mrow0 = bs * 32 + wm * 16 + l4*4;  // C/D batch-row base (+j)

  float c[4];
#pragma unroll
  for (int j = 0; j < 4; ++j)
    c[j] = c0[((size_t)l * BATCH + (mrow0 + j)) * HID + ucol];

  int* cntP = cnt + (l * 4 + bs) * (TSEQ + 1);
  int* cntX = (l > 0) ? cnt + ((l - 1) * 4 + bs) * (TSEQ + 1) : nullptr;
  int* cntC = (l < 5) ? cnt + ((l + 1) * 4 + bs) * (TSEQ + 1) : nullptr;

  const uint16_t* hbL = hbuf + (size_t)l * DEPTH * BATCH * HID;
  const uint16_t* hbX = (l > 0) ? hbuf + (size_t)(l - 1) * DEPTH * BATCH * HID : nullptr;
  uint16_t*       hbO = hbuf + (size_t)l * DEPTH * BATCH * HID;

  for (int t = 0; t < TSEQ; ++t) {
    // early backpressure probe: load only, resolve later (hides L3 latency
    // under the GEMMs). Monotone counters -> direct index, no scan.
    int bpv = 8;
    if (l < 5 && t >= DEPTH)
      bpv = load_flag(&cntC[t - DEPTH]);

    f32x4 acc[4];
#pragma unroll
    for (int gt = 0; gt < 4; ++gt) { f32x4 a = {bias[gt], bias[gt], bias[gt], bias[gt]}; acc[gt] = a; }

    // ---------------- x part (input GEMM, folded per step) ----------------
    if (l == 0) {
      // raw input, fp32, only 128 features (cols 128..255 are the zero-pad)
      const float* xp = xin + ((size_t)mrowA * TSEQ + t) * INFEAT + l4 * 8;
#pragma unroll
      for (int kk = 0; kk < 4; ++kk) {
        bf16x8 af = cvt8(xp + kk * 32);
#pragma unroll
        for (int gt = 0; gt < 4; ++gt)
          acc[gt] = __builtin_amdgcn_mfma_f32_16x16x32_bf16(af, wf[0][gt][kk], acc[gt], 0, 0, 0);
      }
    } else {
      if (load_flag(&cntX[t]) < 8)
        while (load_flag(&cntX[t]) < 8) __builtin_amdgcn_s_sleep(1);
      const uint16_t* hp = hbX + ((size_t)(t & (DEPTH - 1)) * BATCH + mrowA) * HID + l4 * 8;
#pragma unroll
      for (int kk = 0; kk < 8; ++kk) {
        bf16x8 af = load_frag_dc(hp + kk * 32);
#pragma unroll
        for (int gt = 0; gt < 4; ++gt)
          acc[gt] = __builtin_amdgcn_mfma_f32_16x16x32_bf16(af, wf[0][gt][kk], acc[gt], 0, 0, 0);
      }
    }

    // ---------------- h part (recurrent GEMM) ----------------
    if (t == 0) {
      const float* hp = h0 + ((size_t)l * BATCH + mrowA) * HID + l4 * 8;
#pragma unroll
      for (int kk = 0; kk < 8; ++kk) {
        bf16x8 af = cvt8(hp + kk * 32);
#pragma unroll
        for (int gt = 0; gt < 4; ++gt)
          acc[gt] = __builtin_amdgcn_mfma_f32_16x16x32_bf16(af, wf[1][gt][kk], acc[gt], 0, 0, 0);
      }
    } else {
      if (load_flag(&cntP[t - 1]) < 8)
        while (load_flag(&cntP[t - 1]) < 8) { }   // hot wait: poll at load latency
      const uint16_t* hp = hbL + ((size_t)((t - 1) & (DEPTH - 1)) * BATCH + mrowA) * HID + l4 * 8;
#pragma unroll
      for (int kk = 0; kk < 8; ++kk) {
        bf16x8 af = load_frag_dc(hp + kk * 32);
#pragma unroll
        for (int gt = 0; gt < 4; ++gt)
          acc[gt] = __builtin_amdgcn_mfma_f32_16x16x32_bf16(af, wf[1][gt][kk], acc[gt], 0, 0, 0);
      }
    }

    // ---------------- resolve backpressure before overwriting slot ----------------
    if (l < 5 && t >= DEPTH) {
      while (bpv < 8) { __builtin_amdgcn_s_sleep(2); bpv = load_flag(&cntC[t - DEPTH]); }
    }

    // ---------------- gates, state update, h store (device-coherent) ----------------
    uint16_t* op = hbO + (size_t)(t & (DEPTH - 1)) * BATCH * HID;
#pragma unroll
    for (int j = 0; j < 4; ++j) {
      float iv = sigm(acc[0][j]);
      float fv = sigm(acc[1][j]);
      float gv = tanhff(acc[2][j]);
      float ov = sigm(acc[3][j]);
      float cc = fv * c[j] + iv * gv;
      c[j] = cc;
      float hv = ov * tanhff(cc);
      store_u16_dc(op + (size_t)(mrow0 + j) * HID + ucol, (uint16_t)f2bf(hv));
    }
    __syncthreads();   // drains vmcnt -> all 4 waves' stores at coherent point
    if (tid == 0)
      __hip_atomic_fetch_add(&cntP[t], 1, __ATOMIC_RELEASE, __HIP_MEMORY_SCOPE_AGENT);
  }

  // ---------------- FC head: one WG per batch slice ----------------
  if (l == 5 && cg == 0) {
    if (load_flag(&cntP[TSEQ - 1]) < 8)
      while (load_flag(&cntP[TSEQ - 1]) < 8) __builtin_amdgcn_s_sleep(1);
    const uint16_t* hp = hbL + (size_t)((TSEQ - 1) & (DEPTH - 1)) * BATCH * HID;
    for (int p = tid; p < 32 * OUTN; p += 256) {
      const int mr = bs * 32 + p / OUTN, oc = p % OUTN;
      float a = fcb[oc];
      const uint16_t* hr = hp + (size_t)mr * HID;
      const float* wr = fcw + oc * HID;
#pragma unroll
      for (int uu = 0; uu < HID; uu += 4) {
        unsigned long long q = __hip_atomic_load((const unsigned long long*)(hr + uu),
                                                 __ATOMIC_RELAXED, __HIP_MEMORY_SCOPE_AGENT);
        a += bf2f((uint32_t)(q & 0xffff))        * wr[uu]
           + bf2f((uint32_t)((q >> 16) & 0xffff)) * wr[uu + 1]
           + bf2f((uint32_t)((q >> 32) & 0xffff)) * wr[uu + 2]
           + bf2f((uint32_t)(q >> 48))            * wr[uu + 3];
      }
      out[mr * OUTN + oc] = a;
    }
  }
}

extern "C" void kernel_launch(void* const* d_in, const int* in_sizes, int n_in,
                              void* d_out, int out_size, void* d_ws, size_t ws_size,
                              hipStream_t stream) {
  const float* xin = (const float*)d_in[0];
  const float* h0  = (const float*)d_in[1];
  const float* c0  = (const float*)d_in[2];
  const float* wih = (const float*)d_in[3];
  const float* whh = (const float*)d_in[4];
  const float* bih = (const float*)d_in[5];
  const float* bhh = (const float*)d_in[6];
  const float* fcw = (const float*)d_in[7];
  const float* fcb = (const float*)d_in[8];
  float* out = (float*)d_out;

  int* cnt = (int*)d_ws;                       // 24 * 513 * 4B < 64KB
  const size_t cntBytes = 64 * 1024;
  uint16_t* hbuf = (uint16_t*)((char*)d_ws + cntBytes);  // 6*8*128*256*2B ~= 3.1MB

  hipMemsetAsync(d_ws, 0, cntBytes, stream);   // counters start at 0
  lstm_pipeline<<<dim3(192), dim3(256), 0, stream>>>(
      xin, h0, c0, wih, whh, bih, bhh, fcw, fcb, out, cnt, hbuf);
}

// Round 4
// 3341.150 us; speedup vs baseline: 2.6230x; 1.1946x over previous
//
#include <hip/hip_runtime.h>
#include <stdint.h>

#define NLAYER 6
#define BATCH  128
#define HID    256
#define TSEQ   512
#define INFEAT 128
#define DEPTH  8          // h ring-buffer slots per layer (power of 2)
#define OUTN   10

typedef __attribute__((ext_vector_type(8))) short bf16x8;
typedef __attribute__((ext_vector_type(4))) float f32x4;

__device__ __forceinline__ short f2bf(float f) {
  union { float f; uint32_t u; } v; v.f = f;
  uint32_t r = v.u + 0x7fffu + ((v.u >> 16) & 1u);   // RNE
  return (short)(r >> 16);
}
__device__ __forceinline__ float bf2f(uint32_t b) {
  union { uint32_t u; float f; } v; v.u = b << 16;
  return v.f;
}
// convert 8 consecutive fp32 (32B aligned) to a bf16x8 fragment
__device__ __forceinline__ bf16x8 cvt8(const float* p) {
  f32x4 a = *(const f32x4*)p;
  f32x4 b = *(const f32x4*)(p + 4);
  bf16x8 r;
  r[0] = f2bf(a[0]); r[1] = f2bf(a[1]); r[2] = f2bf(a[2]); r[3] = f2bf(a[3]);
  r[4] = f2bf(b[0]); r[5] = f2bf(b[1]); r[6] = f2bf(b[2]); r[7] = f2bf(b[3]);
  return r;
}
__device__ __forceinline__ float sigm(float x)  { return 1.0f / (1.0f + __expf(-x)); }
__device__ __forceinline__ float tanhff(float x){ return 1.0f - 2.0f / (__expf(2.0f * x) + 1.0f); }

// Device-coherent (L2-bypassing) accesses: everything meets at the coherent
// point, so NO acquire/release cache maintenance ops are ever required.
__device__ __forceinline__ bf16x8 load_frag_dc(const uint16_t* p) {
  union { unsigned long long q[2]; bf16x8 v; } u;
  u.q[0] = __hip_atomic_load((const unsigned long long*)p,
                             __ATOMIC_RELAXED, __HIP_MEMORY_SCOPE_AGENT);
  u.q[1] = __hip_atomic_load((const unsigned long long*)(p + 4),
                             __ATOMIC_RELAXED, __HIP_MEMORY_SCOPE_AGENT);
  return u.v;
}
__device__ __forceinline__ void store_u16_dc(uint16_t* p, uint16_t v) {
  __hip_atomic_store(p, v, __ATOMIC_RELAXED, __HIP_MEMORY_SCOPE_AGENT);
}
// 8 producer flags (u16 each, 16B record). Full when every u16 == 1.
__device__ __forceinline__ bool flags_full(const uint16_t* f) {
  unsigned long long a = __hip_atomic_load((const unsigned long long*)f,
                                           __ATOMIC_RELAXED, __HIP_MEMORY_SCOPE_AGENT);
  unsigned long long b = __hip_atomic_load((const unsigned long long*)(f + 4),
                                           __ATOMIC_RELAXED, __HIP_MEMORY_SCOPE_AGENT);
  return (a & b) == 0x0001000100010001ULL;
}

// 192 blocks: 6 layers x 4 batch-slices(32) x 8 unit-groups(32 units).
// Wave (of 4): wm = M-tile (16 batch rows), wu = 16-unit half.
// Weights: register-resident bf16 fragments per thread.
__global__ void __launch_bounds__(256, 1)
lstm_pipeline(const float* __restrict__ xin, const float* __restrict__ h0,
              const float* __restrict__ c0,  const float* __restrict__ wih,
              const float* __restrict__ whh, const float* __restrict__ bih,
              const float* __restrict__ bhh, const float* __restrict__ fcw,
              const float* __restrict__ fcb, float* __restrict__ out,
              uint16_t* flags, uint16_t* hbuf)
{
  // ---- id decode: siblings of one (layer,bslice) share bid%8 (= likely XCD) ----
  const int bid  = blockIdx.x;
  const int xcd  = bid & 7;
  const int slot = bid >> 3;                 // 0..23
  const int grp  = (slot >> 3) * 8 + xcd;    // 0..23  (layer,bslice) group
  const int cg   = slot & 7;                 // unit-group 0..7
  const int l  = grp >> 2;
  const int bs = grp & 3;

  const int tid  = threadIdx.x;
  const int wv   = tid >> 6, lane = tid & 63;
  const int wm   = wv & 1,  wu   = wv >> 1;
  const int l15  = lane & 15, l4 = lane >> 4;

  // ---- resident weight fragments: wf[mat][gate][kblock] ----
  bf16x8 wf[2][4][8];
  float  bias[4];
  {
    const float* Wl[2] = { wih + (size_t)l * 1024 * 256,
                           whh + (size_t)l * 1024 * 256 };
#pragma unroll
    for (int mat = 0; mat < 2; ++mat) {
#pragma unroll
      for (int gt = 0; gt < 4; ++gt) {
        const int Rg = gt * 256 + cg * 32 + wu * 16 + l15;  // gate-row (B j = lane&15)
        const float* rp = Wl[mat] + (size_t)Rg * 256 + l4 * 8;
#pragma unroll
        for (int kk = 0; kk < 8; ++kk)
          wf[mat][gt][kk] = cvt8(rp + kk * 32);
      }
    }
#pragma unroll
    for (int gt = 0; gt < 4; ++gt) {
      const int Rg = gt * 256 + cg * 32 + wu * 16 + l15;
      bias[gt] = bih[l * 1024 + Rg] + bhh[l * 1024 + Rg];
    }
  }

  const int ucol  = cg * 32 + wu * 16 + l15;   // this lane's hidden unit (C/D col)
  const int mrowA = bs * 32 + wm * 16 + l15;   // A-fragment batch row
  const int mrow0 = bs * 32 + wm * 16 + l4*4;  // C/D batch-row base (+j)

  float c[4];
#pragma unroll
  for (int j = 0; j < 4; ++j)
    c[j] = c0[((size_t)l * BATCH + (mrow0 + j)) * HID + ucol];

  // flag records: flags[grp][t] is a 16B record of 8 u16 producer flags
  uint16_t*       fOwn = flags + ((size_t)grp * TSEQ) * 8;
  const uint16_t* fX   = (l > 0) ? flags + ((size_t)((l - 1) * 4 + bs) * TSEQ) * 8 : nullptr;
  const uint16_t* fC   = (l < 5) ? flags + ((size_t)((l + 1) * 4 + bs) * TSEQ) * 8 : nullptr;

  const uint16_t* hbL = hbuf + (size_t)l * DEPTH * BATCH * HID;
  const uint16_t* hbX = (l > 0) ? hbuf + (size_t)(l - 1) * DEPTH * BATCH * HID : nullptr;
  uint16_t*       hbO = hbuf + (size_t)l * DEPTH * BATCH * HID;

  for (int t = 0; t < TSEQ; ++t) {
    f32x4 acc[4];
#pragma unroll
    for (int gt = 0; gt < 4; ++gt) { f32x4 a = {bias[gt], bias[gt], bias[gt], bias[gt]}; acc[gt] = a; }

    // ---------------- x part (input GEMM, folded per step) ----------------
    if (l == 0) {
      // raw input, fp32, only 128 features (cols 128..255 are the zero-pad)
      const float* xp = xin + ((size_t)mrowA * TSEQ + t) * INFEAT + l4 * 8;
#pragma unroll
      for (int kk = 0; kk < 4; ++kk) {
        bf16x8 af = cvt8(xp + kk * 32);
#pragma unroll
        for (int gt = 0; gt < 4; ++gt)
          acc[gt] = __builtin_amdgcn_mfma_f32_16x16x32_bf16(af, wf[0][gt][kk], acc[gt], 0, 0, 0);
      }
    } else {
      const uint16_t* fx = fX + (size_t)t * 8;
      while (!flags_full(fx)) { }   // tight poll: just-in-time on the wavefront
      const uint16_t* hp = hbX + ((size_t)(t & (DEPTH - 1)) * BATCH + mrowA) * HID + l4 * 8;
#pragma unroll
      for (int kk = 0; kk < 8; ++kk) {
        bf16x8 af = load_frag_dc(hp + kk * 32);
#pragma unroll
        for (int gt = 0; gt < 4; ++gt)
          acc[gt] = __builtin_amdgcn_mfma_f32_16x16x32_bf16(af, wf[0][gt][kk], acc[gt], 0, 0, 0);
      }
    }

    // ---------------- h part (recurrent GEMM) ----------------
    if (t == 0) {
      const float* hp = h0 + ((size_t)l * BATCH + mrowA) * HID + l4 * 8;
#pragma unroll
      for (int kk = 0; kk < 8; ++kk) {
        bf16x8 af = cvt8(hp + kk * 8 * 4);
#pragma unroll
        for (int gt = 0; gt < 4; ++gt)
          acc[gt] = __builtin_amdgcn_mfma_f32_16x16x32_bf16(af, wf[1][gt][kk], acc[gt], 0, 0, 0);
      }
    } else {
      const uint16_t* fp = fOwn + (size_t)(t - 1) * 8;
      while (!flags_full(fp)) { }
      const uint16_t* hp = hbL + ((size_t)((t - 1) & (DEPTH - 1)) * BATCH + mrowA) * HID + l4 * 8;
#pragma unroll
      for (int kk = 0; kk < 8; ++kk) {
        bf16x8 af = load_frag_dc(hp + kk * 32);
#pragma unroll
        for (int gt = 0; gt < 4; ++gt)
          acc[gt] = __builtin_amdgcn_mfma_f32_16x16x32_bf16(af, wf[1][gt][kk], acc[gt], 0, 0, 0);
      }
    }

    // ---------------- backpressure: consumer layer must be done with slot ----------------
    if (l < 5 && t >= DEPTH) {
      const uint16_t* fc = fC + (size_t)(t - DEPTH) * 8;
      while (!flags_full(fc)) __builtin_amdgcn_s_sleep(2);
    }

    // ---------------- gates, state update, h store (device-coherent) ----------------
    uint16_t* op = hbO + (size_t)(t & (DEPTH - 1)) * BATCH * HID;
#pragma unroll
    for (int j = 0; j < 4; ++j) {
      float iv = sigm(acc[0][j]);
      float fv = sigm(acc[1][j]);
      float gv = tanhff(acc[2][j]);
      float ov = sigm(acc[3][j]);
      float cc = fv * c[j] + iv * gv;
      c[j] = cc;
      float hv = ov * tanhff(cc);
      store_u16_dc(op + (size_t)(mrow0 + j) * HID + ucol, (uint16_t)f2bf(hv));
    }
    __syncthreads();   // drains vmcnt: all 4 waves' h-stores globally visible
    if (tid == 0)
      store_u16_dc(&fOwn[(size_t)t * 8 + cg], (uint16_t)1);  // one-way flag, no RMW
  }

  // ---------------- FC head: one WG per batch slice ----------------
  if (l == 5 && cg == 0) {
    const uint16_t* fl = fOwn + (size_t)(TSEQ - 1) * 8;
    while (!flags_full(fl)) __builtin_amdgcn_s_sleep(1);
    const uint16_t* hp = hbL + (size_t)((TSEQ - 1) & (DEPTH - 1)) * BATCH * HID;
    for (int p = tid; p < 32 * OUTN; p += 256) {
      const int mr = bs * 32 + p / OUTN, oc = p % OUTN;
      float a = fcb[oc];
      const uint16_t* hr = hp + (size_t)mr * HID;
      const float* wr = fcw + oc * HID;
#pragma unroll
      for (int uu = 0; uu < HID; uu += 4) {
        unsigned long long q = __hip_atomic_load((const unsigned long long*)(hr + uu),
                                                 __ATOMIC_RELAXED, __HIP_MEMORY_SCOPE_AGENT);
        a += bf2f((uint32_t)(q & 0xffff))        * wr[uu]
           + bf2f((uint32_t)((q >> 16) & 0xffff)) * wr[uu + 1]
           + bf2f((uint32_t)((q >> 32) & 0xffff)) * wr[uu + 2]
           + bf2f((uint32_t)(q >> 48))            * wr[uu + 3];
      }
      out[mr * OUTN + oc] = a;
    }
  }
}

extern "C" void kernel_launch(void* const* d_in, const int* in_sizes, int n_in,
                              void* d_out, int out_size, void* d_ws, size_t ws_size,
                              hipStream_t stream) {
  const float* xin = (const float*)d_in[0];
  const float* h0  = (const float*)d_in[1];
  const float* c0  = (const float*)d_in[2];
  const float* wih = (const float*)d_in[3];
  const float* whh = (const float*)d_in[4];
  const float* bih = (const float*)d_in[5];
  const float* bhh = (const float*)d_in[6];
  const float* fcw = (const float*)d_in[7];
  const float* fcb = (const float*)d_in[8];
  float* out = (float*)d_out;

  // flags: 24 groups x 512 t x 8 u16 = 196608 B, zeroed each launch
  uint16_t* flags = (uint16_t*)d_ws;
  const size_t flagBytes = (size_t)24 * TSEQ * 8 * sizeof(uint16_t);
  uint16_t* hbuf = (uint16_t*)((char*)d_ws + 0x40000);   // 256KB offset; 3.1MB ring

  hipMemsetAsync(d_ws, 0, flagBytes, stream);
  lstm_pipeline<<<dim3(192), dim3(256), 0, stream>>>(
      xin, h0, c0, wih, whh, bih, bhh, fcw, fcb, out, flags, hbuf);
}